// Round 1
// 700.202 us; speedup vs baseline: 1.0595x; 1.0595x over previous
//
#include <hip/hip_runtime.h>
#include <hip/hip_bf16.h>

#define H 256
#define W 256
#define CIN 128
#define COUT 128
#define BATCH 8
#define LDA 136  // LDS row stride in bf16 elements (128 + 8 pad, keeps 16B align)

typedef float f32x4 __attribute__((ext_vector_type(4)));
typedef short bf16x8 __attribute__((ext_vector_type(8)));

static __device__ __forceinline__ unsigned short f2bf(float f) {
    unsigned int x = __float_as_uint(f);
    unsigned int r = (x + 0x7fffu + ((x >> 16) & 1u)) >> 16;
    return (unsigned short)r;
}

// Cross-kernel scratch (stream-ordered kernel launches provide visibility).
__device__ float g_s0[CIN];        // s[0][c] (un-normalized)
__device__ float g_bmax[BATCH];    // per-batch max |s[b][c]|
__device__ float g_partial[9 * COUT];  // per-kk partial sum of (w*scale)^2

// ---------------------------------------------------------------------------
// Prep stage 1: s = style @ w_mod + b_mod + 1. One block per batch image.
// Each block: 256 threads, c = t&127, k-range split across two halves.
// Writes g_s0 (b==0 only) and g_bmax[b].
// ---------------------------------------------------------------------------
__global__ __launch_bounds__(256) void mod_style(
    const float* __restrict__ style, const float* __restrict__ w_mod,
    const float* __restrict__ b_mod)
{
    __shared__ float red[256];
    const int t = threadIdx.x;
    const int b = blockIdx.x;
    const int c = t & 127;
    const int half = t >> 7;

    float acc = 0.f;
    const float4* st4 = (const float4*)(style + b * 512 + half * 256);
    const float* wm = w_mod + half * 256 * CIN + c;
    for (int k4 = 0; k4 < 64; ++k4) {
        float4 s4 = st4[k4];
        const float* w = wm + k4 * 4 * CIN;
        acc += s4.x * w[0 * CIN];
        acc += s4.y * w[1 * CIN];
        acc += s4.z * w[2 * CIN];
        acc += s4.w * w[3 * CIN];
    }
    red[t] = acc;
    __syncthreads();
    if (t < 128) {
        float sval = red[t] + red[t + 128] + b_mod[t] + 1.0f;
        if (b == 0) g_s0[t] = sval;
        red[t] = fabsf(sval);
    }
    __syncthreads();
    for (int off = 64; off > 0; off >>= 1) {
        if (t < off) red[t] = fmaxf(red[t], red[t + off]);
        __syncthreads();
    }
    if (t == 0) g_bmax[b] = red[0];
}

// ---------------------------------------------------------------------------
// Prep stage 2: partial demod sums. One block per kk (9 blocks, 256 threads).
// g_partial[kk*128+co] = sum_{ci} (kern[kk][ci][co] * scale[ci])^2
// ---------------------------------------------------------------------------
__global__ __launch_bounds__(256) void demod_partial(
    const float* __restrict__ kern)
{
    __shared__ float scale[CIN];
    __shared__ float red[256];
    const int t = threadIdx.x;
    const int kk = blockIdx.x;
    const int co = t & 127;
    const int half = t >> 7;

    if (t < 128) {
        float m = g_bmax[0];
        #pragma unroll
        for (int i = 1; i < BATCH; ++i) m = fmaxf(m, g_bmax[i]);
        const float he_std = 1.0f / sqrtf(1152.0f);
        scale[t] = g_s0[t] * (1.0f / m) * he_std;
    }
    __syncthreads();

    float ss = 0.f;
    const float* kbase = kern + (size_t)kk * 128 * 128 + co;
    for (int j = 0; j < 64; ++j) {
        int ci = half * 64 + j;
        float wv = kbase[(size_t)ci * 128] * scale[ci];
        ss += wv * wv;
    }
    red[t] = ss;
    __syncthreads();
    if (t < 128) g_partial[kk * 128 + t] = red[t] + red[t + 128];
}

// ---------------------------------------------------------------------------
// Prep stage 3: write pre-swizzled bf16 B-fragments (one unit per thread).
// Unit u = ((kk*4 + kc)*8 + ntile)*64 + lane; each unit 8 bf16 =
// B[k = kc*32 + (lane>>4)*8 + j][n = ntile*16 + (lane&15)], kk = kh*3+kw.
// ---------------------------------------------------------------------------
__global__ __launch_bounds__(256) void swizzle_kernel(
    const float* __restrict__ kern, unsigned short* __restrict__ wprep)
{
    __shared__ float scale[CIN];
    __shared__ float dArr[COUT];
    const int t = threadIdx.x;
    const int u = blockIdx.x * 256 + t;

    if (t < 128) {
        float m = g_bmax[0];
        #pragma unroll
        for (int i = 1; i < BATCH; ++i) m = fmaxf(m, g_bmax[i]);
        const float he_std = 1.0f / sqrtf(1152.0f);
        scale[t] = g_s0[t] * (1.0f / m) * he_std;
        float sum = 0.f;
        #pragma unroll
        for (int g = 0; g < 9; ++g) sum += g_partial[g * 128 + t];
        dArr[t] = rsqrtf(sum + 1e-8f);
    }
    __syncthreads();

    const int lane  = u & 63;
    const int ntile = (u >> 6) & 7;
    const int kc    = (u >> 9) & 3;
    const int kk    = u >> 11;
    const int co  = ntile * 16 + (lane & 15);
    const int cib = kc * 32 + (lane >> 4) * 8;
    const float dv = dArr[co];
    unsigned int packed[4];
    #pragma unroll
    for (int jp = 0; jp < 4; ++jp) {
        int ci0 = cib + jp * 2;
        float w0 = kern[(kk * 128 + ci0)     * 128 + co] * scale[ci0]     * dv;
        float w1 = kern[(kk * 128 + ci0 + 1) * 128 + co] * scale[ci0 + 1] * dv;
        packed[jp] = (unsigned int)f2bf(w0) | ((unsigned int)f2bf(w1) << 16);
    }
    ((uint4*)wprep)[u] = make_uint4(packed[0], packed[1], packed[2], packed[3]);
}

// ---------------------------------------------------------------------------
// Kernel 2: implicit-GEMM conv. Block = 128 pixels (one image row segment)
// x 128 couts; 4 waves in 2x2, each wave 64x64 via 4x4 mfma_f32_16x16x32_bf16.
// Per kh: stage halo row (130 px x 128 cin, fp32->bf16) into LDS once; 3 kw
// positions read shifted windows. B-frags loaded from L2-resident wprep.
// (UNCHANGED this round — prep was the bottleneck.)
// ---------------------------------------------------------------------------
__global__ __launch_bounds__(256) void conv_kernel(
    const float* __restrict__ x, const unsigned short* __restrict__ wprep,
    const float* __restrict__ noise_strength, const float* __restrict__ bias,
    const float* __restrict__ noise, float* __restrict__ out)
{
    __shared__ unsigned short ldsA[130 * LDA];
    const int tid  = threadIdx.x;
    const int lane = tid & 63;
    const int wave = tid >> 6;
    const int wm = wave & 1;   // wave row (pixels)
    const int wn = wave >> 1;  // wave col (couts)
    const int wt = blockIdx.x;        // 0..1 (w tile)
    const int h  = blockIdx.y;        // 0..255
    const int b  = blockIdx.z;        // 0..7
    const int wstart = wt * 128;

    f32x4 acc[4][4];
    const f32x4 zero = {0.f, 0.f, 0.f, 0.f};
    for (int i = 0; i < 4; ++i)
        for (int j = 0; j < 4; ++j) acc[i][j] = zero;

    for (int kh = 0; kh < 3; ++kh) {
        __syncthreads();  // protect LDS from previous iteration's readers
        const int hImg = h + kh - 1;
        const bool rowValid = (hImg >= 0) && (hImg < H);
        const float* rowPtr = x + ((size_t)(b * H + hImg) * W) * CIN;
        for (int idx = tid; idx < 130 * 32; idx += 256) {
            int p  = idx >> 5;       // halo pixel 0..129  (w = wstart-1+p)
            int c4 = idx & 31;       // float4 index in cin
            int wImg = wstart - 1 + p;
            float4 v = make_float4(0.f, 0.f, 0.f, 0.f);
            if (rowValid && (unsigned)wImg < (unsigned)W)
                v = *(const float4*)(rowPtr + (size_t)wImg * CIN + c4 * 4);
            ushort4 u;
            u.x = f2bf(v.x); u.y = f2bf(v.y); u.z = f2bf(v.z); u.w = f2bf(v.w);
            *(ushort4*)&ldsA[p * LDA + c4 * 4] = u;
        }
        __syncthreads();

        #pragma unroll
        for (int kw = 0; kw < 3; ++kw) {
            const int kk = kh * 3 + kw;
            #pragma unroll
            for (int kc = 0; kc < 4; ++kc) {
                bf16x8 bfrag[4], afrag[4];
                const bf16x8* bptr = (const bf16x8*)wprep +
                                     (((kk * 4 + kc) * 8 + wn * 4) * 64 + lane);
                #pragma unroll
                for (int j = 0; j < 4; ++j) bfrag[j] = bptr[j * 64];
                const int ka = kc * 32 + (lane >> 4) * 8;
                #pragma unroll
                for (int i = 0; i < 4; ++i) {
                    int m = wm * 64 + i * 16 + (lane & 15) + kw;  // halo row index
                    afrag[i] = *(const bf16x8*)&ldsA[m * LDA + ka];
                }
                #pragma unroll
                for (int i = 0; i < 4; ++i)
                    #pragma unroll
                    for (int j = 0; j < 4; ++j)
                        acc[i][j] = __builtin_amdgcn_mfma_f32_16x16x32_bf16(
                            afrag[i], bfrag[j], acc[i][j], 0, 0, 0);
            }
        }
    }

    // ---- epilogue: noise + bias + lrelu(0.2)*sqrt(2) ----
    const float ns  = noise_strength[0] * 0.5f;
    const float RT2 = 1.41421356237309515f;
    const size_t pixBase = ((size_t)(b * H + h) * W) + wstart;
    #pragma unroll
    for (int i = 0; i < 4; ++i) {
        const int mbase = wm * 64 + i * 16 + ((lane >> 4) << 2);
        #pragma unroll
        for (int r = 0; r < 4; ++r) {
            const size_t pix = pixBase + (mbase + r);
            const float nz = noise[pix] * ns;
            #pragma unroll
            for (int j = 0; j < 4; ++j) {
                const int col = wn * 64 + j * 16 + (lane & 15);
                float v = acc[i][j][r] + nz + bias[col];
                v = (v >= 0.f ? v : 0.2f * v) * RT2;
                out[pix * COUT + col] = v;
            }
        }
    }
}

extern "C" void kernel_launch(void* const* d_in, const int* in_sizes, int n_in,
                              void* d_out, int out_size, void* d_ws, size_t ws_size,
                              hipStream_t stream) {
    const float* x              = (const float*)d_in[0];
    const float* style          = (const float*)d_in[1];
    const float* kern           = (const float*)d_in[2];
    const float* w_mod          = (const float*)d_in[3];
    const float* b_mod          = (const float*)d_in[4];
    const float* noise_strength = (const float*)d_in[5];
    const float* bias           = (const float*)d_in[6];
    const float* noise          = (const float*)d_in[7];
    float* out = (float*)d_out;
    unsigned short* wprep = (unsigned short*)d_ws;  // 294,912 B of scratch

    hipLaunchKernelGGL(mod_style, dim3(8), dim3(256), 0, stream,
                       style, w_mod, b_mod);
    hipLaunchKernelGGL(demod_partial, dim3(9), dim3(256), 0, stream, kern);
    hipLaunchKernelGGL(swizzle_kernel, dim3(72), dim3(256), 0, stream,
                       kern, wprep);
    hipLaunchKernelGGL(conv_kernel, dim3(2, 256, 8), dim3(256), 0, stream,
                       x, wprep, noise_strength, bias, noise, out);
}

// Round 2
// 601.720 us; speedup vs baseline: 1.2329x; 1.1637x over previous
//
#include <hip/hip_runtime.h>
#include <hip/hip_bf16.h>

#define H 256
#define W 256
#define CIN 128
#define COUT 128
#define BATCH 8
#define LDA 136  // LDS row stride in bf16 elements (128 + 8 pad, keeps 16B align)

typedef float f32x4 __attribute__((ext_vector_type(4)));
typedef short bf16x8 __attribute__((ext_vector_type(8)));

static __device__ __forceinline__ unsigned short f2bf(float f) {
    unsigned int x = __float_as_uint(f);
    unsigned int r = (x + 0x7fffu + ((x >> 16) & 1u)) >> 16;
    return (unsigned short)r;
}

// Cross-kernel scratch (stream-ordered kernel launches provide visibility).
__device__ float g_s0[CIN];        // s[0][c] (un-normalized)
__device__ float g_bmax[BATCH];    // per-batch max |s[b][c]|
__device__ float g_partial[9 * COUT];  // per-kk partial sum of (w*scale)^2

// ---------------------------------------------------------------------------
// Prep stage 1: s = style @ w_mod + b_mod + 1. One block per batch image.
// ---------------------------------------------------------------------------
__global__ __launch_bounds__(256) void mod_style(
    const float* __restrict__ style, const float* __restrict__ w_mod,
    const float* __restrict__ b_mod)
{
    __shared__ float red[256];
    const int t = threadIdx.x;
    const int b = blockIdx.x;
    const int c = t & 127;
    const int half = t >> 7;

    float acc = 0.f;
    const float4* st4 = (const float4*)(style + b * 512 + half * 256);
    const float* wm = w_mod + half * 256 * CIN + c;
    for (int k4 = 0; k4 < 64; ++k4) {
        float4 s4 = st4[k4];
        const float* w = wm + k4 * 4 * CIN;
        acc += s4.x * w[0 * CIN];
        acc += s4.y * w[1 * CIN];
        acc += s4.z * w[2 * CIN];
        acc += s4.w * w[3 * CIN];
    }
    red[t] = acc;
    __syncthreads();
    if (t < 128) {
        float sval = red[t] + red[t + 128] + b_mod[t] + 1.0f;
        if (b == 0) g_s0[t] = sval;
        red[t] = fabsf(sval);
    }
    __syncthreads();
    for (int off = 64; off > 0; off >>= 1) {
        if (t < off) red[t] = fmaxf(red[t], red[t + off]);
        __syncthreads();
    }
    if (t == 0) g_bmax[b] = red[0];
}

// ---------------------------------------------------------------------------
// Prep stage 2: partial demod sums. One block per kk (9 blocks, 256 threads).
// ---------------------------------------------------------------------------
__global__ __launch_bounds__(256) void demod_partial(
    const float* __restrict__ kern)
{
    __shared__ float scale[CIN];
    __shared__ float red[256];
    const int t = threadIdx.x;
    const int kk = blockIdx.x;
    const int co = t & 127;
    const int half = t >> 7;

    if (t < 128) {
        float m = g_bmax[0];
        #pragma unroll
        for (int i = 1; i < BATCH; ++i) m = fmaxf(m, g_bmax[i]);
        const float he_std = 1.0f / sqrtf(1152.0f);
        scale[t] = g_s0[t] * (1.0f / m) * he_std;
    }
    __syncthreads();

    float ss = 0.f;
    const float* kbase = kern + (size_t)kk * 128 * 128 + co;
    for (int j = 0; j < 64; ++j) {
        int ci = half * 64 + j;
        float wv = kbase[(size_t)ci * 128] * scale[ci];
        ss += wv * wv;
    }
    red[t] = ss;
    __syncthreads();
    if (t < 128) g_partial[kk * 128 + t] = red[t] + red[t + 128];
}

// ---------------------------------------------------------------------------
// Prep stage 3: write pre-swizzled bf16 B-fragments (one unit per thread).
// Unit u = ((kk*4 + kc)*8 + ntile)*64 + lane; each unit 8 bf16 =
// B[k = kc*32 + (lane>>4)*8 + j][n = ntile*16 + (lane&15)], kk = kh*3+kw.
// ---------------------------------------------------------------------------
__global__ __launch_bounds__(256) void swizzle_kernel(
    const float* __restrict__ kern, unsigned short* __restrict__ wprep)
{
    __shared__ float scale[CIN];
    __shared__ float dArr[COUT];
    const int t = threadIdx.x;
    const int u = blockIdx.x * 256 + t;

    if (t < 128) {
        float m = g_bmax[0];
        #pragma unroll
        for (int i = 1; i < BATCH; ++i) m = fmaxf(m, g_bmax[i]);
        const float he_std = 1.0f / sqrtf(1152.0f);
        scale[t] = g_s0[t] * (1.0f / m) * he_std;
        float sum = 0.f;
        #pragma unroll
        for (int g = 0; g < 9; ++g) sum += g_partial[g * 128 + t];
        dArr[t] = rsqrtf(sum + 1e-8f);
    }
    __syncthreads();

    const int lane  = u & 63;
    const int ntile = (u >> 6) & 7;
    const int kc    = (u >> 9) & 3;
    const int kk    = u >> 11;
    const int co  = ntile * 16 + (lane & 15);
    const int cib = kc * 32 + (lane >> 4) * 8;
    const float dv = dArr[co];
    unsigned int packed[4];
    #pragma unroll
    for (int jp = 0; jp < 4; ++jp) {
        int ci0 = cib + jp * 2;
        float w0 = kern[(kk * 128 + ci0)     * 128 + co] * scale[ci0]     * dv;
        float w1 = kern[(kk * 128 + ci0 + 1) * 128 + co] * scale[ci0 + 1] * dv;
        packed[jp] = (unsigned int)f2bf(w0) | ((unsigned int)f2bf(w1) << 16);
    }
    ((uint4*)wprep)[u] = make_uint4(packed[0], packed[1], packed[2], packed[3]);
}

// ---------------------------------------------------------------------------
// Kernel 2: implicit-GEMM conv. Block = 128 pixels x 128 couts; 4 waves in
// 2x2, each wave 64x64 via 4x4 mfma_f32_16x16x32_bf16.
// THIS ROUND: 1-phase-deep register pipeline for B-fragments — phase g+1's
// 4 global B-loads are issued before phase g's MFMAs, so the per-phase
// ~300cy L2 wait overlaps compute. afrags streamed per-i (compiler
// schedules fine-grained lgkmcnt). __launch_bounds__(256,3) pins 3 waves/EU.
// ---------------------------------------------------------------------------
__global__ __launch_bounds__(256, 3) void conv_kernel(
    const float* __restrict__ x, const unsigned short* __restrict__ wprep,
    const float* __restrict__ noise_strength, const float* __restrict__ bias,
    const float* __restrict__ noise, float* __restrict__ out)
{
    __shared__ unsigned short ldsA[130 * LDA];
    const int tid  = threadIdx.x;
    const int lane = tid & 63;
    const int wave = tid >> 6;
    const int wm = wave & 1;   // wave row (pixels)
    const int wn = wave >> 1;  // wave col (couts)
    const int wt = blockIdx.x;        // 0..1 (w tile)
    const int h  = blockIdx.y;        // 0..255
    const int b  = blockIdx.z;        // 0..7
    const int wstart = wt * 128;

    f32x4 acc[4][4];
    const f32x4 zero = {0.f, 0.f, 0.f, 0.f};
    for (int i = 0; i < 4; ++i)
        for (int j = 0; j < 4; ++j) acc[i][j] = zero;

    // B-fragment base for this wave: frag j of phase g lives at
    // bb[g*512 + j*64]  (g = kk*4 + kc, kk = kh*3 + kw; wn in {0,1}).
    const bf16x8* bb = (const bf16x8*)wprep + wn * 256 + lane;
    bf16x8 bcur[4];
    #pragma unroll
    for (int j = 0; j < 4; ++j) bcur[j] = bb[j * 64];   // phase 0 preload

    for (int kh = 0; kh < 3; ++kh) {
        __syncthreads();  // protect LDS from previous iteration's readers
        const int hImg = h + kh - 1;
        const bool rowValid = (hImg >= 0) && (hImg < H);
        const float* rowPtr = x + ((size_t)(b * H + hImg) * W) * CIN;
        for (int idx = tid; idx < 130 * 32; idx += 256) {
            int p  = idx >> 5;       // halo pixel 0..129  (w = wstart-1+p)
            int c4 = idx & 31;       // float4 index in cin
            int wImg = wstart - 1 + p;
            float4 v = make_float4(0.f, 0.f, 0.f, 0.f);
            if (rowValid && (unsigned)wImg < (unsigned)W)
                v = *(const float4*)(rowPtr + (size_t)wImg * CIN + c4 * 4);
            ushort4 u;
            u.x = f2bf(v.x); u.y = f2bf(v.y); u.z = f2bf(v.z); u.w = f2bf(v.w);
            *(ushort4*)&ldsA[p * LDA + c4 * 4] = u;
        }
        __syncthreads();

        #pragma unroll
        for (int kw = 0; kw < 3; ++kw) {
            #pragma unroll
            for (int kc = 0; kc < 4; ++kc) {
                const int p12 = kw * 4 + kc;            // 0..11, compile-time
                // next phase index (wraps 35 -> 0; wrap load is harmless,
                // its result is never consumed)
                int gn;
                if (p12 == 11) gn = (kh == 2) ? 0 : (kh + 1) * 12;
                else           gn = kh * 12 + p12 + 1;
                bf16x8 bnxt[4];
                #pragma unroll
                for (int j = 0; j < 4; ++j) bnxt[j] = bb[gn * 512 + j * 64];

                const int ka = kc * 32 + (lane >> 4) * 8;
                #pragma unroll
                for (int i = 0; i < 4; ++i) {
                    int m = wm * 64 + i * 16 + (lane & 15) + kw;  // halo row
                    bf16x8 af = *(const bf16x8*)&ldsA[m * LDA + ka];
                    #pragma unroll
                    for (int j = 0; j < 4; ++j)
                        acc[i][j] = __builtin_amdgcn_mfma_f32_16x16x32_bf16(
                            af, bcur[j], acc[i][j], 0, 0, 0);
                }
                #pragma unroll
                for (int j = 0; j < 4; ++j) bcur[j] = bnxt[j];
            }
        }
    }

    // ---- epilogue: noise + bias + lrelu(0.2)*sqrt(2) ----
    const float ns  = noise_strength[0] * 0.5f;
    const float RT2 = 1.41421356237309515f;
    const size_t pixBase = ((size_t)(b * H + h) * W) + wstart;
    #pragma unroll
    for (int i = 0; i < 4; ++i) {
        const int mbase = wm * 64 + i * 16 + ((lane >> 4) << 2);
        #pragma unroll
        for (int r = 0; r < 4; ++r) {
            const size_t pix = pixBase + (mbase + r);
            const float nz = noise[pix] * ns;
            #pragma unroll
            for (int j = 0; j < 4; ++j) {
                const int col = wn * 64 + j * 16 + (lane & 15);
                float v = acc[i][j][r] + nz + bias[col];
                v = (v >= 0.f ? v : 0.2f * v) * RT2;
                out[pix * COUT + col] = v;
            }
        }
    }
}

extern "C" void kernel_launch(void* const* d_in, const int* in_sizes, int n_in,
                              void* d_out, int out_size, void* d_ws, size_t ws_size,
                              hipStream_t stream) {
    const float* x              = (const float*)d_in[0];
    const float* style          = (const float*)d_in[1];
    const float* kern           = (const float*)d_in[2];
    const float* w_mod          = (const float*)d_in[3];
    const float* b_mod          = (const float*)d_in[4];
    const float* noise_strength = (const float*)d_in[5];
    const float* bias           = (const float*)d_in[6];
    const float* noise          = (const float*)d_in[7];
    float* out = (float*)d_out;
    unsigned short* wprep = (unsigned short*)d_ws;  // 294,912 B of scratch

    hipLaunchKernelGGL(mod_style, dim3(8), dim3(256), 0, stream,
                       style, w_mod, b_mod);
    hipLaunchKernelGGL(demod_partial, dim3(9), dim3(256), 0, stream, kern);
    hipLaunchKernelGGL(swizzle_kernel, dim3(72), dim3(256), 0, stream,
                       kern, wprep);
    hipLaunchKernelGGL(conv_kernel, dim3(2, 256, 8), dim3(256), 0, stream,
                       x, wprep, noise_strength, bias, noise, out);
}